// Round 11
// baseline (192.560 us; speedup 1.0000x reference)
//
#include <hip/hip_runtime.h>
#include <cstdint>
#include <cstddef>

namespace {
constexpr int kN    = 65536;     // nodes
constexpr int kF    = 256;       // feats
constexpr int kC    = 64;        // pools per graph
constexpr int kNPG  = 1024;      // nodes per graph
constexpr int kB    = 64;        // graphs
constexpr int kE    = 2097152;   // edges
constexpr int kK    = kB * kC;   // 4096 global clusters

// d_out offsets (in floats)
constexpr size_t OFF_OUT  = 0;                           // [4096,256]
constexpr size_t OFF_EIDX = (size_t)kK * kF;             // 1048576  [2,262144]
constexpr size_t OFF_ADJ  = OFF_EIDX + 2ull*kB*kC*kC;    // 1572864  [262144]
constexpr size_t OFF_LL   = OFF_ADJ + (size_t)kB*kC*kC;  // 1835008
constexpr size_t OFF_Z    = OFF_LL + 1;                  // 1835009
constexpr size_t OFF_BOUT = OFF_Z + 1;                   // 1835010  [4096]
constexpr size_t OFF_BPTR = OFF_BOUT + kK;               // 1839106  [65]

// ws offsets (bytes). PERM/START overlap PADJ (stream-disjoint lifetimes).
constexpr size_t WS_C    = 0;        // int[65536]
constexpr size_t WS_V    = 262144;   // float[65536]
constexpr size_t WS_VS2  = 524288;   // float[4096]
constexpr size_t WS_A2   = 540672;   // float[256]
constexpr size_t WS_PERM = 544768;   // int[65536]   (dead after k_pool_x)
constexpr size_t WS_STRT = 806912;   // int[64*65]   (dead after k_pool_x)
constexpr size_t WS_PADJ = 544768;   // float[256*4096] = 4 MiB (k_adj onward)
} // namespace

// ---------------------------------------------------------------- constants
__global__ __launch_bounds__(256) void k_const(float* __restrict__ out)
{
    const int i = blockIdx.x * 256 + threadIdx.x;
    constexpr int E2 = 2 * kB * kC * kC;      // 524288
    if (i < E2) {
        const int half = i >= kB*kC*kC;
        const int idx  = half ? i - kB*kC*kC : i;
        const int bb = idx >> 12, rem = idx & 4095;
        const int val = half ? bb*kC + (rem & 63) : bb*kC + (rem >> 6);
        out[OFF_EIDX + i] = (float)val;
    } else if (i < E2 + kK) {
        const int j = i - E2;
        out[OFF_BOUT + j] = (float)(j >> 6);
    } else if (i < E2 + kK + kB + 1) {
        const int j = i - (E2 + kK);
        out[OFF_BPTR + j] = (float)(j * kC);
    }
}

// ------------------------------------------------- K1: logits -> c, v
// GEMM M=65536 N=64 K=256, LDS-FREE. col = lane (wave covers all 64 cols),
// wave owns 8 nodes. W[kk][lane] is per-lane -> 32 VGPR per K-chunk via
// coalesced global loads (L2-hot, once per chunk, NOT per kk). x[n][k] is
// wave-uniform -> one global_load_dwordx4 per (node,k-quad): 1 L1
// transaction feeds 256 FMA-lanes. mbcnt(0,0) (=0 but divergent to LLVM)
// keeps x loads on the VMEM path (s_load would reintroduce the round-8
// lgkmcnt-drain). No barriers, no LDS, no bank conflicts; ~90 VGPR ->
// 5 waves/SIMD. Epilogue: per-node 64-lane shfl max/argmax/sumexp.
__global__ __launch_bounds__(256) void k_logits(
    const float* __restrict__ x, const float* __restrict__ Wm,
    const float* __restrict__ bv, int* __restrict__ carr,
    float* __restrict__ varr)
{
    constexpr int KC = 32;
    const int tid  = threadIdx.x;     // 0..255
    const int lane = tid & 63;        // = output column j
    const int wv   = tid >> 6;        // 0..3
    const int nb   = blockIdx.x * 32 + wv * 8;   // 8 nodes for this wave

    // force divergent (VMEM) path for the wave-uniform x loads
    const int zdiv = __builtin_amdgcn_mbcnt_lo(0u, 0u);   // == 0, divergent
    const float* __restrict__ xb = x + (size_t)nb * kF + zdiv;

    float acc[8];
    {
        const float b = bv[lane];
#pragma unroll
        for (int i = 0; i < 8; ++i) acc[i] = b;
    }

    float wcur[KC];
#pragma unroll 1
    for (int c = 0; c < 8; ++c) {
        // W chunk -> registers (coalesced: lane-contiguous per k-row)
#pragma unroll
        for (int m = 0; m < KC; ++m)
            wcur[m] = Wm[(size_t)(c*KC + m)*kC + lane];
#pragma unroll
        for (int q = 0; q < 8; ++q) {
            float4 xq[8];
#pragma unroll
            for (int i = 0; i < 8; ++i)
                xq[i] = *reinterpret_cast<const float4*>(
                    xb + (size_t)i*kF + c*KC + q*4);
#pragma unroll
            for (int i = 0; i < 8; ++i) {
                acc[i] = fmaf(xq[i].x, wcur[q*4+0], acc[i]);
                acc[i] = fmaf(xq[i].y, wcur[q*4+1], acc[i]);
                acc[i] = fmaf(xq[i].z, wcur[q*4+2], acc[i]);
                acc[i] = fmaf(xq[i].w, wcur[q*4+3], acc[i]);
            }
        }
    }

    // epilogue: per node, 64-lane reduce (max+argmax, then sum of exp)
#pragma unroll
    for (int i = 0; i < 8; ++i) {
        float m = acc[i]; int ci = lane;
#pragma unroll
        for (int off = 32; off > 0; off >>= 1) {
            const float om = __shfl_xor(m, off);
            const int   oc = __shfl_xor(ci, off);
            if (om > m || (om == m && oc < ci)) { m = om; ci = oc; }
        }
        float s = expf(acc[i] - m);
#pragma unroll
        for (int off = 32; off > 0; off >>= 1) s += __shfl_xor(s, off);
        if (lane == i) {
            const float p = 1.0f / s;
            carr[nb + i] = ci;
            varr[nb + i] = (1.0f - p) + p;   // straight-through forward
        }
    }
}

// ------------------------------------- K1b: deterministic stable counting sort
__global__ __launch_bounds__(1024) void k_sort(
    const int* __restrict__ carr, int* __restrict__ perm,
    int* __restrict__ startc)
{
    __shared__ int hist[16][64];
    __shared__ int startS[65];
    const int g = blockIdx.x;
    const int tid = threadIdx.x;
    const int w = tid >> 6, lane = tid & 63;
    const int c = carr[g*kNPG + tid];
    hist[tid >> 6][tid & 63] = 0;
    __syncthreads();
    unsigned long long mm = ~0ull;
#pragma unroll
    for (int b = 0; b < 6; ++b) {
        const unsigned long long bal = __ballot((c >> b) & 1);
        mm &= ((c >> b) & 1) ? bal : ~bal;
    }
    const unsigned long long ltmask =
        (lane == 0) ? 0ull : (~0ull >> (64 - lane));
    const int rank_in_wave = __popcll(mm & ltmask);
    const int leader = __ffsll((unsigned long long)mm) - 1;
    if (lane == leader) hist[w][c] = __popcll(mm);
    __syncthreads();
    if (w == 0) {
        int tot = 0;
#pragma unroll
        for (int i = 0; i < 16; ++i) tot += hist[i][lane];
        int pre = tot;
#pragma unroll
        for (int off = 1; off < 64; off <<= 1) {
            const int t = __shfl_up(pre, off);
            if (lane >= off) pre += t;
        }
        startS[lane + 1] = pre;
        if (lane == 0) startS[0] = 0;
    }
    __syncthreads();
    int before = startS[c];
    for (int i = 0; i < w; ++i) before += hist[i][c];
    perm[g*kNPG + before + rank_in_wave] = g*kNPG + tid;
    if (tid < 65) startc[g*65 + tid] = startS[tid];
}

// ------------------------------------- K2: out = S^T x (+ vs2) — atomic-FREE
__global__ __launch_bounds__(1024) void k_pool_x(
    const float* __restrict__ x, const int* __restrict__ perm,
    const int* __restrict__ startc, const float* __restrict__ varr,
    float* __restrict__ out, float* __restrict__ vs2)
{
    const int tid  = threadIdx.x;
    const int g    = blockIdx.x >> 3;
    const int fh   = blockIdx.x & 7;
    const int w    = tid >> 6;
    const int lane = tid & 63;
    const int q    = lane & 7;      // feat quad (float4)
    const int sub  = lane >> 3;     // node slot 0..7
    const int fbase = fh*32 + q*4;
#pragma unroll
    for (int cc = 0; cc < 4; ++cc) {
        const int c = w*4 + cc;
        const int s = startc[g*65 + c];
        const int e = startc[g*65 + c + 1];
        float ax = 0.f, ay = 0.f, az = 0.f, aw = 0.f, v2 = 0.f;
        for (int base = s + sub; base < e; base += 8) {
            const int n = perm[(size_t)g*kNPG + base];
            const float v = varr[n];
            const float4 xv = *reinterpret_cast<const float4*>(
                x + (size_t)n*kF + fbase);
            ax = fmaf(v, xv.x, ax); ay = fmaf(v, xv.y, ay);
            az = fmaf(v, xv.z, az); aw = fmaf(v, xv.w, aw);
            v2 = fmaf(v, v, v2);
        }
#pragma unroll
        for (int off = 8; off < 64; off <<= 1) {
            ax += __shfl_xor(ax, off); ay += __shfl_xor(ay, off);
            az += __shfl_xor(az, off); aw += __shfl_xor(aw, off);
            v2 += __shfl_xor(v2, off);
        }
        if (sub == 0) {
            const float4 o = {ax, ay, az, aw};
            *reinterpret_cast<float4*>(
                out + OFF_OUT + (size_t)(g*kC + c)*kF + fbase) = o;
        }
        if (fh == 0 && lane == 0) vs2[g*kC + c] = v2;
    }
}

// ------------------------------------- K4: adjacency partials (+ a2 partial)
__global__ __launch_bounds__(1024) void k_adj(
    const int* __restrict__ ei, const float* __restrict__ ew,
    const int* __restrict__ carr, const float* __restrict__ varr,
    float* __restrict__ padj, float* __restrict__ a2p)
{
    __shared__ float adj[kC*kC];   // 16 KB
    __shared__ float vls[kNPG];    // 4 KB
    __shared__ int   cls[kNPG];    // 4 KB
    __shared__ float wred[16];
    const int tid = threadIdx.x;
    const int bid = blockIdx.x;             // 256 blocks = 64 graphs x 4
    const int g   = bid >> 2;
    for (int i = tid; i < kC*kC; i += 1024) adj[i] = 0.f;
    vls[tid] = varr[g*kNPG + tid];
    cls[tid] = carr[g*kNPG + tid];
    __syncthreads();
    const int e0 = bid * 8192;
    float a2l = 0.f;
#pragma unroll
    for (int it = 0; it < 8; ++it) {
        const int e  = e0 + it*1024 + tid;
        const int sn = ei[e]      & (kNPG - 1);
        const int dn = ei[kE + e] & (kNPG - 1);
        const float wv = ew[e];
        a2l += wv * wv;
        atomicAdd(&adj[cls[sn]*kC + cls[dn]], wv * vls[sn] * vls[dn]);
    }
    __syncthreads();
#pragma unroll
    for (int r = 0; r < 4; ++r) {
        const int lin = r*1024 + tid;
        padj[(size_t)bid*4096 + lin] = adj[lin];
    }
#pragma unroll
    for (int off = 32; off > 0; off >>= 1) a2l += __shfl_down(a2l, off);
    if ((tid & 63) == 0) wred[tid >> 6] = a2l;
    __syncthreads();
    if (tid == 0) {
        float s = 0.f;
#pragma unroll
        for (int wv = 0; wv < 16; ++wv) s += wred[wv];
        a2p[bid] = s;
    }
}

// ------------------------------------- K5: merge adjacency partials
__global__ __launch_bounds__(256) void k_adj_merge(
    const float* __restrict__ padj, float* __restrict__ out)
{
    const int id = blockIdx.x*256 + threadIdx.x;   // < 262144
    const int g = id >> 12, idx = id & 4095;
    float s = 0.f;
#pragma unroll
    for (int sp = 0; sp < 4; ++sp) s += padj[(size_t)(g*4 + sp)*4096 + idx];
    out[OFF_ADJ + id] = s;
}

// ------------------------------------- K6: link_loss scalar
__global__ __launch_bounds__(256) void k_final(
    const float* __restrict__ vs2, const float* __restrict__ a2p,
    float* __restrict__ out)
{
    const int tid = threadIdx.x;
    float p2l = 0.f, apl = 0.f;
#pragma unroll
    for (int r = 0; r < 16; ++r) {
        const int k = r*256 + tid;
        const float t = vs2[k];
        p2l += t*t;
        const int g = k >> 6, cc = k & 63;
        apl += out[OFF_ADJ + (size_t)g*4096 + cc*65];   // diagonal entries
    }
    float a2l = a2p[tid];
#pragma unroll
    for (int off = 32; off > 0; off >>= 1) {
        p2l += __shfl_down(p2l, off);
        apl += __shfl_down(apl, off);
        a2l += __shfl_down(a2l, off);
    }
    __shared__ float red[3][4];
    if ((tid & 63) == 0) {
        red[0][tid>>6] = p2l; red[1][tid>>6] = apl; red[2][tid>>6] = a2l;
    }
    __syncthreads();
    if (tid == 0) {
        const float p2 = red[0][0]+red[0][1]+red[0][2]+red[0][3];
        const float ap = red[1][0]+red[1][1]+red[1][2]+red[1][3];
        const float a2 = red[2][0]+red[2][1]+red[2][2]+red[2][3];
        const float val = a2 - 2.0f*ap + p2;
        out[OFF_LL] = sqrtf(fmaxf(val, 0.f)) / (float)kE;
        out[OFF_Z]  = 0.0f;
    }
}

// ----------------------------------------------------------------- launch
extern "C" void kernel_launch(void* const* d_in, const int* in_sizes, int n_in,
                              void* d_out, int out_size, void* d_ws, size_t ws_size,
                              hipStream_t stream)
{
    const float* x  = (const float*)d_in[0];
    const int*   ei = (const int*)d_in[1];
    const float* ew = (const float*)d_in[2];
    const float* Wm = (const float*)d_in[5];
    const float* bv = (const float*)d_in[6];
    float* out = (float*)d_out;
    char*  ws  = (char*)d_ws;
    int*   carr  = (int*)(ws + WS_C);
    float* varr  = (float*)(ws + WS_V);
    float* vs2   = (float*)(ws + WS_VS2);
    float* a2p   = (float*)(ws + WS_A2);
    int*   perm  = (int*)(ws + WS_PERM);
    int*   strt  = (int*)(ws + WS_STRT);
    float* padj  = (float*)(ws + WS_PADJ);

    k_const    <<<2065, 256, 0, stream>>>(out);
    k_logits   <<<2048, 256, 0, stream>>>(x, Wm, bv, carr, varr);
    k_sort     <<<64,  1024, 0, stream>>>(carr, perm, strt);
    k_pool_x   <<<512, 1024, 0, stream>>>(x, perm, strt, varr, out, vs2);
    k_adj      <<<256, 1024, 0, stream>>>(ei, ew, carr, varr, padj, a2p);
    k_adj_merge<<<1024, 256, 0, stream>>>(padj, out);
    k_final    <<<1,    256, 0, stream>>>(vs2, a2p, out);
}

// Round 12
// 139.884 us; speedup vs baseline: 1.3766x; 1.3766x over previous
//
#include <hip/hip_runtime.h>
#include <cstdint>
#include <cstddef>

namespace {
constexpr int kN    = 65536;     // nodes
constexpr int kF    = 256;       // feats
constexpr int kC    = 64;        // pools per graph
constexpr int kNPG  = 1024;      // nodes per graph
constexpr int kB    = 64;        // graphs
constexpr int kE    = 2097152;   // edges
constexpr int kK    = kB * kC;   // 4096 global clusters

// d_out offsets (in floats)
constexpr size_t OFF_OUT  = 0;                           // [4096,256]
constexpr size_t OFF_EIDX = (size_t)kK * kF;             // 1048576  [2,262144]
constexpr size_t OFF_ADJ  = OFF_EIDX + 2ull*kB*kC*kC;    // 1572864  [262144]
constexpr size_t OFF_LL   = OFF_ADJ + (size_t)kB*kC*kC;  // 1835008
constexpr size_t OFF_Z    = OFF_LL + 1;                  // 1835009
constexpr size_t OFF_BOUT = OFF_Z + 1;                   // 1835010  [4096]
constexpr size_t OFF_BPTR = OFF_BOUT + kK;               // 1839106  [65]

// ws offsets (bytes). Overlaps are stream-time-disjoint:
//   WT   (k_const->k_logits)  1048576..1114112
//   PERM/STRT (k_sort->k_pool_x)
//   PADJ (k_adj->k_adj_merge) overlaps PERM/STRT/WT ranges but only after
//   their last readers have finished.
constexpr size_t WS_C    = 0;        // int[65536]
constexpr size_t WS_V    = 262144;   // float[65536]
constexpr size_t WS_VS2  = 524288;   // float[4096]
constexpr size_t WS_A2   = 540672;   // float[256]
constexpr size_t WS_PERM = 544768;   // int[65536]
constexpr size_t WS_STRT = 806912;   // int[64*65]
constexpr size_t WS_WT   = 1048576;  // float[16384]  W transposed-packed
constexpr size_t WS_PADJ = 544768;   // float[256*4096] = 4 MiB (k_adj onward)
} // namespace

// ---------------------------------------------------------------- constants
// also packs W into Wt2[q][c][4]: Wt2 flat[j], j = q*256 + c*4 + jj
//   <-> W[(4q+jj)*64 + c]   (one dwordx4 per lane = W[4q..4q+3][lane])
__global__ __launch_bounds__(256) void k_const(float* __restrict__ out,
                                               const float* __restrict__ Wm,
                                               float* __restrict__ wt)
{
    const int i = blockIdx.x * 256 + threadIdx.x;
    constexpr int E2 = 2 * kB * kC * kC;      // 524288
    constexpr int B3 = E2 + kK + kB + 1;      // 528449
    if (i < E2) {
        const int half = i >= kB*kC*kC;
        const int idx  = half ? i - kB*kC*kC : i;
        const int bb = idx >> 12, rem = idx & 4095;
        const int val = half ? bb*kC + (rem & 63) : bb*kC + (rem >> 6);
        out[OFF_EIDX + i] = (float)val;
    } else if (i < E2 + kK) {
        const int j = i - E2;
        out[OFF_BOUT + j] = (float)(j >> 6);
    } else if (i < B3) {
        const int j = i - (E2 + kK);
        out[OFF_BPTR + j] = (float)(j * kC);
    } else if (i < B3 + 16384) {
        const int j = i - B3;
        const int q = j >> 8, r = j & 255, c = r >> 2, jj = r & 3;
        wt[j] = Wm[(size_t)(4*q + jj)*kC + c];
    }
}

// ------------------------------------------------- K1: logits -> c, v
// GEMM M=65536 N=64 K=256, LDS-FREE, col = lane. Wave owns 8 nodes.
// x: wave-uniform rows -> s_load_dwordx4 into SGPRs (double-buffered
// ping-pong, batched -> ONE lgkmcnt drain per 64-cyc compute block; no DS
// ops exist, so no per-kk drains as in round 8). W: per-lane dwordx4 from
// the packed Wt2 (coalesced 1KB/instr, L2-hot, 64 VMEM/wave total).
// FMA = v_fmac(sgpr_x, vgpr_w) -> pure VALU inner loop.
// ~30 VGPR / ~80 SGPR, grid 2048x256 -> 8 waves/SIMD.
__global__ __launch_bounds__(256) void k_logits(
    const float* __restrict__ x, const float* __restrict__ wt,
    const float* __restrict__ bv, int* __restrict__ carr,
    float* __restrict__ varr)
{
    const int tid  = threadIdx.x;     // 0..255
    const int lane = tid & 63;        // output column j
    const int wv   = __builtin_amdgcn_readfirstlane(tid >> 6);
    const int nb   = blockIdx.x * 32 + wv * 8;     // 8 nodes for this wave
    const float* __restrict__ xrow = x + (size_t)nb * kF;   // wave-uniform
    const float* __restrict__ wtl  = wt + lane * 4;         // per-lane

    float acc[8];
    {
        const float b = bv[lane];
#pragma unroll
        for (int i = 0; i < 8; ++i) acc[i] = b;
    }

    float4 xA[8], xB[8], wA, wB;
    // prologue: sub-chunk q=0 into A
#pragma unroll
    for (int i = 0; i < 8; ++i)
        xA[i] = *reinterpret_cast<const float4*>(xrow + i*kF);
    wA = *reinterpret_cast<const float4*>(wtl);

#pragma unroll 1
    for (int q2 = 0; q2 < 32; ++q2) {
        // prefetch odd sub-chunk (q = 2*q2+1) into B
#pragma unroll
        for (int i = 0; i < 8; ++i)
            xB[i] = *reinterpret_cast<const float4*>(
                xrow + i*kF + (q2*2 + 1)*4);
        wB = *reinterpret_cast<const float4*>(wtl + (size_t)(q2*2 + 1)*256);
        // compute even sub-chunk from A
#pragma unroll
        for (int i = 0; i < 8; ++i) {
            acc[i] = fmaf(xA[i].x, wA.x, acc[i]);
            acc[i] = fmaf(xA[i].y, wA.y, acc[i]);
            acc[i] = fmaf(xA[i].z, wA.z, acc[i]);
            acc[i] = fmaf(xA[i].w, wA.w, acc[i]);
        }
        // prefetch next even sub-chunk (q = 2*q2+2) into A
        if (q2 < 31) {
#pragma unroll
            for (int i = 0; i < 8; ++i)
                xA[i] = *reinterpret_cast<const float4*>(
                    xrow + i*kF + (q2*2 + 2)*4);
            wA = *reinterpret_cast<const float4*>(
                wtl + (size_t)(q2*2 + 2)*256);
        }
        // compute odd sub-chunk from B
#pragma unroll
        for (int i = 0; i < 8; ++i) {
            acc[i] = fmaf(xB[i].x, wB.x, acc[i]);
            acc[i] = fmaf(xB[i].y, wB.y, acc[i]);
            acc[i] = fmaf(xB[i].z, wB.z, acc[i]);
            acc[i] = fmaf(xB[i].w, wB.w, acc[i]);
        }
    }

    // epilogue: per node, 64-lane reduce (max+argmax, then sum of exp)
#pragma unroll
    for (int i = 0; i < 8; ++i) {
        float m = acc[i]; int ci = lane;
#pragma unroll
        for (int off = 32; off > 0; off >>= 1) {
            const float om = __shfl_xor(m, off);
            const int   oc = __shfl_xor(ci, off);
            if (om > m || (om == m && oc < ci)) { m = om; ci = oc; }
        }
        float s = expf(acc[i] - m);
#pragma unroll
        for (int off = 32; off > 0; off >>= 1) s += __shfl_xor(s, off);
        if (lane == i) {
            const float p = 1.0f / s;
            carr[nb + i] = ci;
            varr[nb + i] = (1.0f - p) + p;   // straight-through forward
        }
    }
}

// ------------------------------------- K1b: deterministic stable counting sort
__global__ __launch_bounds__(1024) void k_sort(
    const int* __restrict__ carr, int* __restrict__ perm,
    int* __restrict__ startc)
{
    __shared__ int hist[16][64];
    __shared__ int startS[65];
    const int g = blockIdx.x;
    const int tid = threadIdx.x;
    const int w = tid >> 6, lane = tid & 63;
    const int c = carr[g*kNPG + tid];
    hist[tid >> 6][tid & 63] = 0;
    __syncthreads();
    unsigned long long mm = ~0ull;
#pragma unroll
    for (int b = 0; b < 6; ++b) {
        const unsigned long long bal = __ballot((c >> b) & 1);
        mm &= ((c >> b) & 1) ? bal : ~bal;
    }
    const unsigned long long ltmask =
        (lane == 0) ? 0ull : (~0ull >> (64 - lane));
    const int rank_in_wave = __popcll(mm & ltmask);
    const int leader = __ffsll((unsigned long long)mm) - 1;
    if (lane == leader) hist[w][c] = __popcll(mm);
    __syncthreads();
    if (w == 0) {
        int tot = 0;
#pragma unroll
        for (int i = 0; i < 16; ++i) tot += hist[i][lane];
        int pre = tot;
#pragma unroll
        for (int off = 1; off < 64; off <<= 1) {
            const int t = __shfl_up(pre, off);
            if (lane >= off) pre += t;
        }
        startS[lane + 1] = pre;
        if (lane == 0) startS[0] = 0;
    }
    __syncthreads();
    int before = startS[c];
    for (int i = 0; i < w; ++i) before += hist[i][c];
    perm[g*kNPG + before + rank_in_wave] = g*kNPG + tid;
    if (tid < 65) startc[g*65 + tid] = startS[tid];
}

// ------------------------------------- K2: out = S^T x (+ vs2) — atomic-FREE
__global__ __launch_bounds__(1024) void k_pool_x(
    const float* __restrict__ x, const int* __restrict__ perm,
    const int* __restrict__ startc, const float* __restrict__ varr,
    float* __restrict__ out, float* __restrict__ vs2)
{
    const int tid  = threadIdx.x;
    const int g    = blockIdx.x >> 3;
    const int fh   = blockIdx.x & 7;
    const int w    = tid >> 6;
    const int lane = tid & 63;
    const int q    = lane & 7;      // feat quad (float4)
    const int sub  = lane >> 3;     // node slot 0..7
    const int fbase = fh*32 + q*4;
#pragma unroll
    for (int cc = 0; cc < 4; ++cc) {
        const int c = w*4 + cc;
        const int s = startc[g*65 + c];
        const int e = startc[g*65 + c + 1];
        float ax = 0.f, ay = 0.f, az = 0.f, aw = 0.f, v2 = 0.f;
        for (int base = s + sub; base < e; base += 8) {
            const int n = perm[(size_t)g*kNPG + base];
            const float v = varr[n];
            const float4 xv = *reinterpret_cast<const float4*>(
                x + (size_t)n*kF + fbase);
            ax = fmaf(v, xv.x, ax); ay = fmaf(v, xv.y, ay);
            az = fmaf(v, xv.z, az); aw = fmaf(v, xv.w, aw);
            v2 = fmaf(v, v, v2);
        }
#pragma unroll
        for (int off = 8; off < 64; off <<= 1) {
            ax += __shfl_xor(ax, off); ay += __shfl_xor(ay, off);
            az += __shfl_xor(az, off); aw += __shfl_xor(aw, off);
            v2 += __shfl_xor(v2, off);
        }
        if (sub == 0) {
            const float4 o = {ax, ay, az, aw};
            *reinterpret_cast<float4*>(
                out + OFF_OUT + (size_t)(g*kC + c)*kF + fbase) = o;
        }
        if (fh == 0 && lane == 0) vs2[g*kC + c] = v2;
    }
}

// ------------------------------------- K4: adjacency partials (+ a2 partial)
__global__ __launch_bounds__(1024) void k_adj(
    const int* __restrict__ ei, const float* __restrict__ ew,
    const int* __restrict__ carr, const float* __restrict__ varr,
    float* __restrict__ padj, float* __restrict__ a2p)
{
    __shared__ float adj[kC*kC];   // 16 KB
    __shared__ float vls[kNPG];    // 4 KB
    __shared__ int   cls[kNPG];    // 4 KB
    __shared__ float wred[16];
    const int tid = threadIdx.x;
    const int bid = blockIdx.x;             // 256 blocks = 64 graphs x 4
    const int g   = bid >> 2;
    for (int i = tid; i < kC*kC; i += 1024) adj[i] = 0.f;
    vls[tid] = varr[g*kNPG + tid];
    cls[tid] = carr[g*kNPG + tid];
    __syncthreads();
    const int e0 = bid * 8192;
    float a2l = 0.f;
#pragma unroll
    for (int it = 0; it < 8; ++it) {
        const int e  = e0 + it*1024 + tid;
        const int sn = ei[e]      & (kNPG - 1);
        const int dn = ei[kE + e] & (kNPG - 1);
        const float wv = ew[e];
        a2l += wv * wv;
        atomicAdd(&adj[cls[sn]*kC + cls[dn]], wv * vls[sn] * vls[dn]);
    }
    __syncthreads();
#pragma unroll
    for (int r = 0; r < 4; ++r) {
        const int lin = r*1024 + tid;
        padj[(size_t)bid*4096 + lin] = adj[lin];
    }
#pragma unroll
    for (int off = 32; off > 0; off >>= 1) a2l += __shfl_down(a2l, off);
    if ((tid & 63) == 0) wred[tid >> 6] = a2l;
    __syncthreads();
    if (tid == 0) {
        float s = 0.f;
#pragma unroll
        for (int wv = 0; wv < 16; ++wv) s += wred[wv];
        a2p[bid] = s;
    }
}

// ------------------------------------- K5: merge adjacency partials
__global__ __launch_bounds__(256) void k_adj_merge(
    const float* __restrict__ padj, float* __restrict__ out)
{
    const int id = blockIdx.x*256 + threadIdx.x;   // < 262144
    const int g = id >> 12, idx = id & 4095;
    float s = 0.f;
#pragma unroll
    for (int sp = 0; sp < 4; ++sp) s += padj[(size_t)(g*4 + sp)*4096 + idx];
    out[OFF_ADJ + id] = s;
}

// ------------------------------------- K6: link_loss scalar
__global__ __launch_bounds__(256) void k_final(
    const float* __restrict__ vs2, const float* __restrict__ a2p,
    float* __restrict__ out)
{
    const int tid = threadIdx.x;
    float p2l = 0.f, apl = 0.f;
#pragma unroll
    for (int r = 0; r < 16; ++r) {
        const int k = r*256 + tid;
        const float t = vs2[k];
        p2l += t*t;
        const int g = k >> 6, cc = k & 63;
        apl += out[OFF_ADJ + (size_t)g*4096 + cc*65];   // diagonal entries
    }
    float a2l = a2p[tid];
#pragma unroll
    for (int off = 32; off > 0; off >>= 1) {
        p2l += __shfl_down(p2l, off);
        apl += __shfl_down(apl, off);
        a2l += __shfl_down(a2l, off);
    }
    __shared__ float red[3][4];
    if ((tid & 63) == 0) {
        red[0][tid>>6] = p2l; red[1][tid>>6] = apl; red[2][tid>>6] = a2l;
    }
    __syncthreads();
    if (tid == 0) {
        const float p2 = red[0][0]+red[0][1]+red[0][2]+red[0][3];
        const float ap = red[1][0]+red[1][1]+red[1][2]+red[1][3];
        const float a2 = red[2][0]+red[2][1]+red[2][2]+red[2][3];
        const float val = a2 - 2.0f*ap + p2;
        out[OFF_LL] = sqrtf(fmaxf(val, 0.f)) / (float)kE;
        out[OFF_Z]  = 0.0f;
    }
}

// ----------------------------------------------------------------- launch
extern "C" void kernel_launch(void* const* d_in, const int* in_sizes, int n_in,
                              void* d_out, int out_size, void* d_ws, size_t ws_size,
                              hipStream_t stream)
{
    const float* x  = (const float*)d_in[0];
    const int*   ei = (const int*)d_in[1];
    const float* ew = (const float*)d_in[2];
    const float* Wm = (const float*)d_in[5];
    const float* bv = (const float*)d_in[6];
    float* out = (float*)d_out;
    char*  ws  = (char*)d_ws;
    int*   carr  = (int*)(ws + WS_C);
    float* varr  = (float*)(ws + WS_V);
    float* vs2   = (float*)(ws + WS_VS2);
    float* a2p   = (float*)(ws + WS_A2);
    int*   perm  = (int*)(ws + WS_PERM);
    int*   strt  = (int*)(ws + WS_STRT);
    float* wt    = (float*)(ws + WS_WT);
    float* padj  = (float*)(ws + WS_PADJ);

    k_const    <<<2129, 256, 0, stream>>>(out, Wm, wt);
    k_logits   <<<2048, 256, 0, stream>>>(x, wt, bv, carr, varr);
    k_sort     <<<64,  1024, 0, stream>>>(carr, perm, strt);
    k_pool_x   <<<512, 1024, 0, stream>>>(x, perm, strt, varr, out, vs2);
    k_adj      <<<256, 1024, 0, stream>>>(ei, ew, carr, varr, padj, a2p);
    k_adj_merge<<<1024, 256, 0, stream>>>(padj, out);
    k_final    <<<1,    256, 0, stream>>>(vs2, a2p, out);
}

// Round 13
// 93.267 us; speedup vs baseline: 2.0646x; 1.4998x over previous
//
#include <hip/hip_runtime.h>
#include <cstdint>
#include <cstddef>

typedef __attribute__((ext_vector_type(8))) short short8;
typedef __attribute__((ext_vector_type(4))) float f32x4;

namespace {
constexpr int kN    = 65536;     // nodes
constexpr int kF    = 256;       // feats
constexpr int kC    = 64;        // pools per graph
constexpr int kNPG  = 1024;      // nodes per graph
constexpr int kB    = 64;        // graphs
constexpr int kE    = 2097152;   // edges
constexpr int kK    = kB * kC;   // 4096 global clusters

// d_out offsets (in floats)
constexpr size_t OFF_OUT  = 0;                           // [4096,256]
constexpr size_t OFF_EIDX = (size_t)kK * kF;             // 1048576  [2,262144]
constexpr size_t OFF_ADJ  = OFF_EIDX + 2ull*kB*kC*kC;    // 1572864  [262144]
constexpr size_t OFF_LL   = OFF_ADJ + (size_t)kB*kC*kC;  // 1835008
constexpr size_t OFF_Z    = OFF_LL + 1;                  // 1835009
constexpr size_t OFF_BOUT = OFF_Z + 1;                   // 1835010  [4096]
constexpr size_t OFF_BPTR = OFF_BOUT + kK;               // 1839106  [65]

// ws offsets (bytes). Overlaps are stream-time-disjoint:
//   WTH/WTL (k_const->k_logits), PERM/STRT (k_sort->k_pool_x) both die
//   before k_adj writes PADJ over the same range.
constexpr size_t WS_C    = 0;        // int[65536]
constexpr size_t WS_V    = 262144;   // float[65536]
constexpr size_t WS_VS2  = 524288;   // float[4096]
constexpr size_t WS_A2   = 540672;   // float[256]
constexpr size_t WS_PERM = 544768;   // int[65536]
constexpr size_t WS_STRT = 806912;   // int[64*65]
constexpr size_t WS_WTH  = 1048576;  // ushort[16384] W^T hi  (bf16)
constexpr size_t WS_WTL  = 1081344;  // ushort[16384] W^T lo  (bf16)
constexpr size_t WS_PADJ = 544768;   // float[256*4096] = 4 MiB (k_adj onward)

__device__ __forceinline__ unsigned short bf16_rn(float f)
{
    const unsigned int b = __float_as_uint(f);
    return (unsigned short)((b + 0x7fffu + ((b >> 16) & 1u)) >> 16);
}
} // namespace

// ---------------------------------------------------------------- constants
// + packs W into bf16 hi/lo transposed: wth/wtl[c*256+k] ~ W[k*64+c]
__global__ __launch_bounds__(256) void k_const(float* __restrict__ out,
                                               const float* __restrict__ Wm,
                                               unsigned short* __restrict__ wth,
                                               unsigned short* __restrict__ wtl)
{
    const int i = blockIdx.x * 256 + threadIdx.x;
    constexpr int E2 = 2 * kB * kC * kC;      // 524288
    constexpr int B3 = E2 + kK + kB + 1;      // 528449
    if (i < E2) {
        const int half = i >= kB*kC*kC;
        const int idx  = half ? i - kB*kC*kC : i;
        const int bb = idx >> 12, rem = idx & 4095;
        const int val = half ? bb*kC + (rem & 63) : bb*kC + (rem >> 6);
        out[OFF_EIDX + i] = (float)val;
    } else if (i < E2 + kK) {
        const int j = i - E2;
        out[OFF_BOUT + j] = (float)(j >> 6);
    } else if (i < B3) {
        const int j = i - (E2 + kK);
        out[OFF_BPTR + j] = (float)(j * kC);
    } else if (i < B3 + 16384) {
        const int j = i - B3;
        const int c = j >> 8, k = j & 255;
        const float w = Wm[(size_t)k*kC + c];
        const unsigned short h = bf16_rn(w);
        const float hf = __uint_as_float((unsigned int)h << 16);
        wth[j] = h;
        wtl[j] = bf16_rn(w - hf);
    }
}

// ------------------------------------------------- K1: logits -> c, v
// MFMA 16x16x32_bf16, split-bf16 4-term (x=xh+xl, W=wh+wl; acc fp32):
// representation error ~2^-18 -> logit error ~2e-6 (= fp32 reorder noise).
// Wave = 16 nodes (M=16) x 64 cols (4 N-tiles); 8 K-steps.
// A-frag: row=lane&15, k=(lane>>4)*8+j (8 consecutive fp32 from x, split
// in-register). B-frag: col=lane&15 from pre-split wth/wtl (L1-hot 64KB).
// C/D: col=lane&15, row=(lane>>4)*4+reg [m89-verified]. No LDS, no
// barriers; grid 1024x256 -> 16 waves/CU. x read once (64MB) = the floor.
__global__ __launch_bounds__(256) void k_logits(
    const float* __restrict__ x, const unsigned short* __restrict__ wth,
    const unsigned short* __restrict__ wtl, const float* __restrict__ bv,
    int* __restrict__ carr, float* __restrict__ varr)
{
    const int tid  = threadIdx.x;
    const int lane = tid & 63;
    const int wv   = tid >> 6;
    const int nbase = blockIdx.x * 64 + wv * 16;
    const int l15  = lane & 15;       // A-row (input) and D-col (output)
    const int kgrp = lane >> 4;       // 0..3
    const float* __restrict__ xrow =
        x + (size_t)(nbase + l15) * kF + kgrp * 8;

    f32x4 acc[4];
#pragma unroll
    for (int nt = 0; nt < 4; ++nt) acc[nt] = f32x4{0.f, 0.f, 0.f, 0.f};

#pragma unroll 1
    for (int ks = 0; ks < 8; ++ks) {
        const float4 xa = *reinterpret_cast<const float4*>(xrow + ks*32);
        const float4 xb = *reinterpret_cast<const float4*>(xrow + ks*32 + 4);
        const float xv[8] = {xa.x, xa.y, xa.z, xa.w,
                             xb.x, xb.y, xb.z, xb.w};
        short8 ah, al;
#pragma unroll
        for (int j = 0; j < 8; ++j) {
            const unsigned short h = bf16_rn(xv[j]);
            const float hf = __uint_as_float((unsigned int)h << 16);
            ah[j] = (short)h;
            al[j] = (short)bf16_rn(xv[j] - hf);
        }
        const int koff = ks*32 + kgrp*8;
#pragma unroll
        for (int nt = 0; nt < 4; ++nt) {
            const size_t wo = (size_t)(nt*16 + l15)*kF + koff;
            const short8 bh = *reinterpret_cast<const short8*>(wth + wo);
            const short8 bl = *reinterpret_cast<const short8*>(wtl + wo);
            acc[nt] = __builtin_amdgcn_mfma_f32_16x16x32_bf16(
                ah, bh, acc[nt], 0, 0, 0);
            acc[nt] = __builtin_amdgcn_mfma_f32_16x16x32_bf16(
                al, bh, acc[nt], 0, 0, 0);
            acc[nt] = __builtin_amdgcn_mfma_f32_16x16x32_bf16(
                ah, bl, acc[nt], 0, 0, 0);
            acc[nt] = __builtin_amdgcn_mfma_f32_16x16x32_bf16(
                al, bl, acc[nt], 0, 0, 0);
        }
    }

    // bias: lane holds D[node=(kgrp)*4+reg][col=nt*16+l15]
#pragma unroll
    for (int nt = 0; nt < 4; ++nt) {
        const float b = bv[nt*16 + l15];
#pragma unroll
        for (int r = 0; r < 4; ++r) acc[nt][r] += b;
    }

    // per-node softmax-argmax: node n = kgrp*4 + r; 16 lanes share kgrp.
#pragma unroll
    for (int r = 0; r < 4; ++r) {
        float m = acc[0][r]; int ci = l15;
#pragma unroll
        for (int nt = 1; nt < 4; ++nt) {
            if (acc[nt][r] > m) { m = acc[nt][r]; ci = nt*16 + l15; }
        }
#pragma unroll
        for (int off = 1; off < 16; off <<= 1) {
            const float om = __shfl_xor(m, off);
            const int   oc = __shfl_xor(ci, off);
            if (om > m || (om == m && oc < ci)) { m = om; ci = oc; }
        }
        float s = 0.f;
#pragma unroll
        for (int nt = 0; nt < 4; ++nt) s += expf(acc[nt][r] - m);
#pragma unroll
        for (int off = 1; off < 16; off <<= 1) s += __shfl_xor(s, off);
        if (l15 == r) {
            const float p = 1.0f / s;
            const int n = nbase + kgrp*4 + r;
            carr[n] = ci;
            varr[n] = (1.0f - p) + p;   // straight-through forward
        }
    }
}

// ------------------------------------- K1b: deterministic stable counting sort
__global__ __launch_bounds__(1024) void k_sort(
    const int* __restrict__ carr, int* __restrict__ perm,
    int* __restrict__ startc)
{
    __shared__ int hist[16][64];
    __shared__ int startS[65];
    const int g = blockIdx.x;
    const int tid = threadIdx.x;
    const int w = tid >> 6, lane = tid & 63;
    const int c = carr[g*kNPG + tid];
    hist[tid >> 6][tid & 63] = 0;
    __syncthreads();
    unsigned long long mm = ~0ull;
#pragma unroll
    for (int b = 0; b < 6; ++b) {
        const unsigned long long bal = __ballot((c >> b) & 1);
        mm &= ((c >> b) & 1) ? bal : ~bal;
    }
    const unsigned long long ltmask =
        (lane == 0) ? 0ull : (~0ull >> (64 - lane));
    const int rank_in_wave = __popcll(mm & ltmask);
    const int leader = __ffsll((unsigned long long)mm) - 1;
    if (lane == leader) hist[w][c] = __popcll(mm);
    __syncthreads();
    if (w == 0) {
        int tot = 0;
#pragma unroll
        for (int i = 0; i < 16; ++i) tot += hist[i][lane];
        int pre = tot;
#pragma unroll
        for (int off = 1; off < 64; off <<= 1) {
            const int t = __shfl_up(pre, off);
            if (lane >= off) pre += t;
        }
        startS[lane + 1] = pre;
        if (lane == 0) startS[0] = 0;
    }
    __syncthreads();
    int before = startS[c];
    for (int i = 0; i < w; ++i) before += hist[i][c];
    perm[g*kNPG + before + rank_in_wave] = g*kNPG + tid;
    if (tid < 65) startc[g*65 + tid] = startS[tid];
}

// ------------------------------------- K2: out = S^T x (+ vs2) — atomic-FREE
__global__ __launch_bounds__(1024) void k_pool_x(
    const float* __restrict__ x, const int* __restrict__ perm,
    const int* __restrict__ startc, const float* __restrict__ varr,
    float* __restrict__ out, float* __restrict__ vs2)
{
    const int tid  = threadIdx.x;
    const int g    = blockIdx.x >> 3;
    const int fh   = blockIdx.x & 7;
    const int w    = tid >> 6;
    const int lane = tid & 63;
    const int q    = lane & 7;      // feat quad (float4)
    const int sub  = lane >> 3;     // node slot 0..7
    const int fbase = fh*32 + q*4;
#pragma unroll
    for (int cc = 0; cc < 4; ++cc) {
        const int c = w*4 + cc;
        const int s = startc[g*65 + c];
        const int e = startc[g*65 + c + 1];
        float ax = 0.f, ay = 0.f, az = 0.f, aw = 0.f, v2 = 0.f;
        for (int base = s + sub; base < e; base += 8) {
            const int n = perm[(size_t)g*kNPG + base];
            const float v = varr[n];
            const float4 xv = *reinterpret_cast<const float4*>(
                x + (size_t)n*kF + fbase);
            ax = fmaf(v, xv.x, ax); ay = fmaf(v, xv.y, ay);
            az = fmaf(v, xv.z, az); aw = fmaf(v, xv.w, aw);
            v2 = fmaf(v, v, v2);
        }
#pragma unroll
        for (int off = 8; off < 64; off <<= 1) {
            ax += __shfl_xor(ax, off); ay += __shfl_xor(ay, off);
            az += __shfl_xor(az, off); aw += __shfl_xor(aw, off);
            v2 += __shfl_xor(v2, off);
        }
        if (sub == 0) {
            const float4 o = {ax, ay, az, aw};
            *reinterpret_cast<float4*>(
                out + OFF_OUT + (size_t)(g*kC + c)*kF + fbase) = o;
        }
        if (fh == 0 && lane == 0) vs2[g*kC + c] = v2;
    }
}

// ------------------------------------- K4: adjacency partials (+ a2 partial)
__global__ __launch_bounds__(1024) void k_adj(
    const int* __restrict__ ei, const float* __restrict__ ew,
    const int* __restrict__ carr, const float* __restrict__ varr,
    float* __restrict__ padj, float* __restrict__ a2p)
{
    __shared__ float adj[kC*kC];   // 16 KB
    __shared__ float vls[kNPG];    // 4 KB
    __shared__ int   cls[kNPG];    // 4 KB
    __shared__ float wred[16];
    const int tid = threadIdx.x;
    const int bid = blockIdx.x;             // 256 blocks = 64 graphs x 4
    const int g   = bid >> 2;
    for (int i = tid; i < kC*kC; i += 1024) adj[i] = 0.f;
    vls[tid] = varr[g*kNPG + tid];
    cls[tid] = carr[g*kNPG + tid];
    __syncthreads();
    const int e0 = bid * 8192;
    float a2l = 0.f;
#pragma unroll
    for (int it = 0; it < 8; ++it) {
        const int e  = e0 + it*1024 + tid;
        const int sn = ei[e]      & (kNPG - 1);
        const int dn = ei[kE + e] & (kNPG - 1);
        const float wv = ew[e];
        a2l += wv * wv;
        atomicAdd(&adj[cls[sn]*kC + cls[dn]], wv * vls[sn] * vls[dn]);
    }
    __syncthreads();
#pragma unroll
    for (int r = 0; r < 4; ++r) {
        const int lin = r*1024 + tid;
        padj[(size_t)bid*4096 + lin] = adj[lin];
    }
#pragma unroll
    for (int off = 32; off > 0; off >>= 1) a2l += __shfl_down(a2l, off);
    if ((tid & 63) == 0) wred[tid >> 6] = a2l;
    __syncthreads();
    if (tid == 0) {
        float s = 0.f;
#pragma unroll
        for (int wv = 0; wv < 16; ++wv) s += wred[wv];
        a2p[bid] = s;
    }
}

// ------------------------------------- K5: merge adjacency partials
__global__ __launch_bounds__(256) void k_adj_merge(
    const float* __restrict__ padj, float* __restrict__ out)
{
    const int id = blockIdx.x*256 + threadIdx.x;   // < 262144
    const int g = id >> 12, idx = id & 4095;
    float s = 0.f;
#pragma unroll
    for (int sp = 0; sp < 4; ++sp) s += padj[(size_t)(g*4 + sp)*4096 + idx];
    out[OFF_ADJ + id] = s;
}

// ------------------------------------- K6: link_loss scalar
__global__ __launch_bounds__(256) void k_final(
    const float* __restrict__ vs2, const float* __restrict__ a2p,
    float* __restrict__ out)
{
    const int tid = threadIdx.x;
    float p2l = 0.f, apl = 0.f;
#pragma unroll
    for (int r = 0; r < 16; ++r) {
        const int k = r*256 + tid;
        const float t = vs2[k];
        p2l += t*t;
        const int g = k >> 6, cc = k & 63;
        apl += out[OFF_ADJ + (size_t)g*4096 + cc*65];   // diagonal entries
    }
    float a2l = a2p[tid];
#pragma unroll
    for (int off = 32; off > 0; off >>= 1) {
        p2l += __shfl_down(p2l, off);
        apl += __shfl_down(apl, off);
        a2l += __shfl_down(a2l, off);
    }
    __shared__ float red[3][4];
    if ((tid & 63) == 0) {
        red[0][tid>>6] = p2l; red[1][tid>>6] = apl; red[2][tid>>6] = a2l;
    }
    __syncthreads();
    if (tid == 0) {
        const float p2 = red[0][0]+red[0][1]+red[0][2]+red[0][3];
        const float ap = red[1][0]+red[1][1]+red[1][2]+red[1][3];
        const float a2 = red[2][0]+red[2][1]+red[2][2]+red[2][3];
        const float val = a2 - 2.0f*ap + p2;
        out[OFF_LL] = sqrtf(fmaxf(val, 0.f)) / (float)kE;
        out[OFF_Z]  = 0.0f;
    }
}

// ----------------------------------------------------------------- launch
extern "C" void kernel_launch(void* const* d_in, const int* in_sizes, int n_in,
                              void* d_out, int out_size, void* d_ws, size_t ws_size,
                              hipStream_t stream)
{
    const float* x  = (const float*)d_in[0];
    const int*   ei = (const int*)d_in[1];
    const float* ew = (const float*)d_in[2];
    const float* Wm = (const float*)d_in[5];
    const float* bv = (const float*)d_in[6];
    float* out = (float*)d_out;
    char*  ws  = (char*)d_ws;
    int*   carr  = (int*)(ws + WS_C);
    float* varr  = (float*)(ws + WS_V);
    float* vs2   = (float*)(ws + WS_VS2);
    float* a2p   = (float*)(ws + WS_A2);
    int*   perm  = (int*)(ws + WS_PERM);
    int*   strt  = (int*)(ws + WS_STRT);
    unsigned short* wth = (unsigned short*)(ws + WS_WTH);
    unsigned short* wtl = (unsigned short*)(ws + WS_WTL);
    float* padj  = (float*)(ws + WS_PADJ);

    k_const    <<<2129, 256, 0, stream>>>(out, Wm, wth, wtl);
    k_logits   <<<1024, 256, 0, stream>>>(x, wth, wtl, bv, carr, varr);
    k_sort     <<<64,  1024, 0, stream>>>(carr, perm, strt);
    k_pool_x   <<<512, 1024, 0, stream>>>(x, perm, strt, varr, out, vs2);
    k_adj      <<<256, 1024, 0, stream>>>(ei, ew, carr, varr, padj, a2p);
    k_adj_merge<<<1024, 256, 0, stream>>>(padj, out);
    k_final    <<<1,    256, 0, stream>>>(vs2, a2p, out);
}

// Round 14
// 79.495 us; speedup vs baseline: 2.4223x; 1.1732x over previous
//
#include <hip/hip_runtime.h>
#include <cstdint>
#include <cstddef>

typedef __attribute__((ext_vector_type(8))) short short8;
typedef __attribute__((ext_vector_type(4))) float f32x4;

#define GLOAD_LDS16(gsrc, ldst) \
    __builtin_amdgcn_global_load_lds( \
        (const __attribute__((address_space(1))) void*)(gsrc), \
        (__attribute__((address_space(3))) void*)(ldst), 16, 0, 0)

namespace {
constexpr int kN    = 65536;     // nodes
constexpr int kF    = 256;       // feats
constexpr int kC    = 64;        // pools per graph
constexpr int kNPG  = 1024;      // nodes per graph
constexpr int kB    = 64;        // graphs
constexpr int kE    = 2097152;   // edges
constexpr int kK    = kB * kC;   // 4096 global clusters

// d_out offsets (in floats)
constexpr size_t OFF_OUT  = 0;                           // [4096,256]
constexpr size_t OFF_EIDX = (size_t)kK * kF;             // 1048576  [2,262144]
constexpr size_t OFF_ADJ  = OFF_EIDX + 2ull*kB*kC*kC;    // 1572864  [262144]
constexpr size_t OFF_LL   = OFF_ADJ + (size_t)kB*kC*kC;  // 1835008
constexpr size_t OFF_Z    = OFF_LL + 1;                  // 1835009
constexpr size_t OFF_BOUT = OFF_Z + 1;                   // 1835010  [4096]
constexpr size_t OFF_BPTR = OFF_BOUT + kK;               // 1839106  [65]

// ws offsets (bytes). Overlaps are stream-time-disjoint (WTH/WTL + PERM/STRT
// die before k_adj writes PADJ over the same range).
constexpr size_t WS_C    = 0;        // int[65536]
constexpr size_t WS_V    = 262144;   // float[65536]
constexpr size_t WS_VS2  = 524288;   // float[4096]
constexpr size_t WS_A2   = 540672;   // float[256]
constexpr size_t WS_PERM = 544768;   // int[65536]
constexpr size_t WS_STRT = 806912;   // int[64*65]
constexpr size_t WS_WTH  = 1048576;  // ushort[16384] W^T hi  (bf16)
constexpr size_t WS_WTL  = 1081344;  // ushort[16384] W^T lo  (bf16)
constexpr size_t WS_PADJ = 544768;   // float[256*4096] = 4 MiB (k_adj onward)

__device__ __forceinline__ unsigned short bf16_rn(float f)
{
    const unsigned int b = __float_as_uint(f);
    return (unsigned short)((b + 0x7fffu + ((b >> 16) & 1u)) >> 16);
}
} // namespace

// ---------------------------------------------------------------- constants
// + packs W into bf16 hi/lo transposed: wth/wtl[c*256+k] ~ W[k*64+c]
__global__ __launch_bounds__(256) void k_const(float* __restrict__ out,
                                               const float* __restrict__ Wm,
                                               unsigned short* __restrict__ wth,
                                               unsigned short* __restrict__ wtl)
{
    const int i = blockIdx.x * 256 + threadIdx.x;
    constexpr int E2 = 2 * kB * kC * kC;      // 524288
    constexpr int B3 = E2 + kK + kB + 1;      // 528449
    if (i < E2) {
        const int half = i >= kB*kC*kC;
        const int idx  = half ? i - kB*kC*kC : i;
        const int bb = idx >> 12, rem = idx & 4095;
        const int val = half ? bb*kC + (rem & 63) : bb*kC + (rem >> 6);
        out[OFF_EIDX + i] = (float)val;
    } else if (i < E2 + kK) {
        const int j = i - E2;
        out[OFF_BOUT + j] = (float)(j >> 6);
    } else if (i < B3) {
        const int j = i - (E2 + kK);
        out[OFF_BPTR + j] = (float)(j * kC);
    } else if (i < B3 + 16384) {
        const int j = i - B3;
        const int c = j >> 8, k = j & 255;
        const float w = Wm[(size_t)k*kC + c];
        const unsigned short h = bf16_rn(w);
        const float hf = __uint_as_float((unsigned int)h << 16);
        wth[j] = h;
        wtl[j] = bf16_rn(w - hf);
    }
}

// ------------------------------------------------- K1: logits -> c, v
// m97-style staged MFMA. Block = 256 thr (4 waves) x 128 nodes; grid 512
// (2 blocks/CU; barriers of the two blocks overlap). x staged into LDS via
// fire-and-forget global_load_lds (16B/lane, 4 instr/wave/chunk) -> deep
// MLP without VGPR cost; counted vmcnt(4) (never 0 mid-loop, T4) + barrier.
// Compute: per chunk, wave owns 32 nodes (2 M-tiles): 2 ds_read_b128 per
// tile (node-row-major [128][32]f, ~4-way = data floor), rounded hi/lo
// split (r13 numerics, proven), 4-term 16x16x32_bf16 MFMA; W per-lane
// from L2-hot wth/wtl. Math identical to round 13.
__global__ __launch_bounds__(256) void k_logits(
    const float* __restrict__ x, const unsigned short* __restrict__ wth,
    const unsigned short* __restrict__ wtl, const float* __restrict__ bv,
    int* __restrict__ carr, float* __restrict__ varr)
{
    __shared__ float xs[2][128 * 32];   // 2 x 16 KB, [node][32 k-floats]
    const int tid  = threadIdx.x;
    const int lane = tid & 63;
    const int w    = tid >> 6;          // wave 0..3
    const int nbase = blockIdx.x * 128;
    const int l15  = lane & 15;
    const int kgrp = lane >> 4;         // 0..3

    // staging: wave w stages groups g = w*4+i (8 nodes x 128B each);
    // lane l -> node g*8 + (l>>3), float-offset (l&7)*4 (16B)
    const int snode = lane >> 3;
    const int soff  = (lane & 7) * 4;

    f32x4 acc[2][4];
#pragma unroll
    for (int mt = 0; mt < 2; ++mt)
#pragma unroll
        for (int nt = 0; nt < 4; ++nt)
            acc[mt][nt] = f32x4{0.f, 0.f, 0.f, 0.f};

    // prologue: stage chunk 0 into buffer 0
#pragma unroll
    for (int i = 0; i < 4; ++i) {
        const int g = w*4 + i;
        const float* src = x + (size_t)(nbase + g*8 + snode)*kF + soff;
        GLOAD_LDS16(src, &xs[0][g*256]);
    }

#pragma unroll 1
    for (int c = 0; c < 8; ++c) {
        if (c < 7) {
#pragma unroll
            for (int i = 0; i < 4; ++i) {
                const int g = w*4 + i;
                const float* src = x + (size_t)(nbase + g*8 + snode)*kF
                                     + (c+1)*32 + soff;
                GLOAD_LDS16(src, &xs[(c+1) & 1][g*256]);
            }
            asm volatile("s_waitcnt vmcnt(4)" ::: "memory");
        } else {
            asm volatile("s_waitcnt vmcnt(0)" ::: "memory");
        }
        __syncthreads();   // chunk c landed for all waves; old buf free

        const float* __restrict__ xb = &xs[c & 1][0];
        const int koff = c*32 + kgrp*8;
        short8 bh[4], bl[4];
#pragma unroll
        for (int nt = 0; nt < 4; ++nt) {
            const size_t wo = (size_t)(nt*16 + l15)*kF + koff;
            bh[nt] = *reinterpret_cast<const short8*>(wth + wo);
            bl[nt] = *reinterpret_cast<const short8*>(wtl + wo);
        }
#pragma unroll
        for (int mt = 0; mt < 2; ++mt) {
            const int a = (w*32 + mt*16 + l15)*32 + kgrp*8;
            const float4 xa = *reinterpret_cast<const float4*>(&xb[a]);
            const float4 xc = *reinterpret_cast<const float4*>(&xb[a+4]);
            const float xv[8] = {xa.x, xa.y, xa.z, xa.w,
                                 xc.x, xc.y, xc.z, xc.w};
            short8 ah, al;
#pragma unroll
            for (int j = 0; j < 8; ++j) {
                const unsigned short h = bf16_rn(xv[j]);
                const float hf = __uint_as_float((unsigned int)h << 16);
                ah[j] = (short)h;
                al[j] = (short)bf16_rn(xv[j] - hf);
            }
#pragma unroll
            for (int nt = 0; nt < 4; ++nt) {
                acc[mt][nt] = __builtin_amdgcn_mfma_f32_16x16x32_bf16(
                    ah, bh[nt], acc[mt][nt], 0, 0, 0);
                acc[mt][nt] = __builtin_amdgcn_mfma_f32_16x16x32_bf16(
                    al, bh[nt], acc[mt][nt], 0, 0, 0);
                acc[mt][nt] = __builtin_amdgcn_mfma_f32_16x16x32_bf16(
                    ah, bl[nt], acc[mt][nt], 0, 0, 0);
                acc[mt][nt] = __builtin_amdgcn_mfma_f32_16x16x32_bf16(
                    al, bl[nt], acc[mt][nt], 0, 0, 0);
            }
        }
        __syncthreads();   // all waves done reading buf[c&1] (restaged c+2)
    }

    // bias + per-node softmax-argmax (D: col=nt*16+l15, row=kgrp*4+r)
#pragma unroll
    for (int mt = 0; mt < 2; ++mt) {
#pragma unroll
        for (int nt = 0; nt < 4; ++nt) {
            const float b = bv[nt*16 + l15];
#pragma unroll
            for (int r = 0; r < 4; ++r) acc[mt][nt][r] += b;
        }
#pragma unroll
        for (int r = 0; r < 4; ++r) {
            float m = acc[mt][0][r]; int ci = l15;
#pragma unroll
            for (int nt = 1; nt < 4; ++nt) {
                if (acc[mt][nt][r] > m) { m = acc[mt][nt][r]; ci = nt*16 + l15; }
            }
#pragma unroll
            for (int off = 1; off < 16; off <<= 1) {
                const float om = __shfl_xor(m, off);
                const int   oc = __shfl_xor(ci, off);
                if (om > m || (om == m && oc < ci)) { m = om; ci = oc; }
            }
            float s = 0.f;
#pragma unroll
            for (int nt = 0; nt < 4; ++nt) s += expf(acc[mt][nt][r] - m);
#pragma unroll
            for (int off = 1; off < 16; off <<= 1) s += __shfl_xor(s, off);
            if (l15 == r) {
                const float p = 1.0f / s;
                const int n = nbase + w*32 + mt*16 + kgrp*4 + r;
                carr[n] = ci;
                varr[n] = (1.0f - p) + p;   // straight-through forward
            }
        }
    }
}

// ------------------------------------- K1b: deterministic stable counting sort
__global__ __launch_bounds__(1024) void k_sort(
    const int* __restrict__ carr, int* __restrict__ perm,
    int* __restrict__ startc)
{
    __shared__ int hist[16][64];
    __shared__ int startS[65];
    const int g = blockIdx.x;
    const int tid = threadIdx.x;
    const int w = tid >> 6, lane = tid & 63;
    const int c = carr[g*kNPG + tid];
    hist[tid >> 6][tid & 63] = 0;
    __syncthreads();
    unsigned long long mm = ~0ull;
#pragma unroll
    for (int b = 0; b < 6; ++b) {
        const unsigned long long bal = __ballot((c >> b) & 1);
        mm &= ((c >> b) & 1) ? bal : ~bal;
    }
    const unsigned long long ltmask =
        (lane == 0) ? 0ull : (~0ull >> (64 - lane));
    const int rank_in_wave = __popcll(mm & ltmask);
    const int leader = __ffsll((unsigned long long)mm) - 1;
    if (lane == leader) hist[w][c] = __popcll(mm);
    __syncthreads();
    if (w == 0) {
        int tot = 0;
#pragma unroll
        for (int i = 0; i < 16; ++i) tot += hist[i][lane];
        int pre = tot;
#pragma unroll
        for (int off = 1; off < 64; off <<= 1) {
            const int t = __shfl_up(pre, off);
            if (lane >= off) pre += t;
        }
        startS[lane + 1] = pre;
        if (lane == 0) startS[0] = 0;
    }
    __syncthreads();
    int before = startS[c];
    for (int i = 0; i < w; ++i) before += hist[i][c];
    perm[g*kNPG + before + rank_in_wave] = g*kNPG + tid;
    if (tid < 65) startc[g*65 + tid] = startS[tid];
}

// ------------------------------------- K2: out = S^T x (+ vs2) — atomic-FREE
__global__ __launch_bounds__(1024) void k_pool_x(
    const float* __restrict__ x, const int* __restrict__ perm,
    const int* __restrict__ startc, const float* __restrict__ varr,
    float* __restrict__ out, float* __restrict__ vs2)
{
    const int tid  = threadIdx.x;
    const int g    = blockIdx.x >> 3;
    const int fh   = blockIdx.x & 7;
    const int w    = tid >> 6;
    const int lane = tid & 63;
    const int q    = lane & 7;      // feat quad (float4)
    const int sub  = lane >> 3;     // node slot 0..7
    const int fbase = fh*32 + q*4;
#pragma unroll
    for (int cc = 0; cc < 4; ++cc) {
        const int c = w*4 + cc;
        const int s = startc[g*65 + c];
        const int e = startc[g*65 + c + 1];
        float ax = 0.f, ay = 0.f, az = 0.f, aw = 0.f, v2 = 0.f;
        for (int base = s + sub; base < e; base += 8) {
            const int n = perm[(size_t)g*kNPG + base];
            const float v = varr[n];
            const float4 xv = *reinterpret_cast<const float4*>(
                x + (size_t)n*kF + fbase);
            ax = fmaf(v, xv.x, ax); ay = fmaf(v, xv.y, ay);
            az = fmaf(v, xv.z, az); aw = fmaf(v, xv.w, aw);
            v2 = fmaf(v, v, v2);
        }
#pragma unroll
        for (int off = 8; off < 64; off <<= 1) {
            ax += __shfl_xor(ax, off); ay += __shfl_xor(ay, off);
            az += __shfl_xor(az, off); aw += __shfl_xor(aw, off);
            v2 += __shfl_xor(v2, off);
        }
        if (sub == 0) {
            const float4 o = {ax, ay, az, aw};
            *reinterpret_cast<float4*>(
                out + OFF_OUT + (size_t)(g*kC + c)*kF + fbase) = o;
        }
        if (fh == 0 && lane == 0) vs2[g*kC + c] = v2;
    }
}

// ------------------------------------- K4: adjacency partials (+ a2 partial)
__global__ __launch_bounds__(1024) void k_adj(
    const int* __restrict__ ei, const float* __restrict__ ew,
    const int* __restrict__ carr, const float* __restrict__ varr,
    float* __restrict__ padj, float* __restrict__ a2p)
{
    __shared__ float adj[kC*kC];   // 16 KB
    __shared__ float vls[kNPG];    // 4 KB
    __shared__ int   cls[kNPG];    // 4 KB
    __shared__ float wred[16];
    const int tid = threadIdx.x;
    const int bid = blockIdx.x;             // 256 blocks = 64 graphs x 4
    const int g   = bid >> 2;
    for (int i = tid; i < kC*kC; i += 1024) adj[i] = 0.f;
    vls[tid] = varr[g*kNPG + tid];
    cls[tid] = carr[g*kNPG + tid];
    __syncthreads();
    const int e0 = bid * 8192;
    float a2l = 0.f;
#pragma unroll
    for (int it = 0; it < 8; ++it) {
        const int e  = e0 + it*1024 + tid;
        const int sn = ei[e]      & (kNPG - 1);
        const int dn = ei[kE + e] & (kNPG - 1);
        const float wv = ew[e];
        a2l += wv * wv;
        atomicAdd(&adj[cls[sn]*kC + cls[dn]], wv * vls[sn] * vls[dn]);
    }
    __syncthreads();
#pragma unroll
    for (int r = 0; r < 4; ++r) {
        const int lin = r*1024 + tid;
        padj[(size_t)bid*4096 + lin] = adj[lin];
    }
#pragma unroll
    for (int off = 32; off > 0; off >>= 1) a2l += __shfl_down(a2l, off);
    if ((tid & 63) == 0) wred[tid >> 6] = a2l;
    __syncthreads();
    if (tid == 0) {
        float s = 0.f;
#pragma unroll
        for (int wv = 0; wv < 16; ++wv) s += wred[wv];
        a2p[bid] = s;
    }
}

// ------------------------------------- K5: merge adjacency partials
__global__ __launch_bounds__(256) void k_adj_merge(
    const float* __restrict__ padj, float* __restrict__ out)
{
    const int id = blockIdx.x*256 + threadIdx.x;   // < 262144
    const int g = id >> 12, idx = id & 4095;
    float s = 0.f;
#pragma unroll
    for (int sp = 0; sp < 4; ++sp) s += padj[(size_t)(g*4 + sp)*4096 + idx];
    out[OFF_ADJ + id] = s;
}

// ------------------------------------- K6: link_loss scalar
__global__ __launch_bounds__(256) void k_final(
    const float* __restrict__ vs2, const float* __restrict__ a2p,
    float* __restrict__ out)
{
    const int tid = threadIdx.x;
    float p2l = 0.f, apl = 0.f;
#pragma unroll
    for (int r = 0; r < 16; ++r) {
        const int k = r*256 + tid;
        const float t = vs2[k];
        p2l += t*t;
        const int g = k >> 6, cc = k & 63;
        apl += out[OFF_ADJ + (size_t)g*4096 + cc*65];   // diagonal entries
    }
    float a2l = a2p[tid];
#pragma unroll
    for (int off = 32; off > 0; off >>= 1) {
        p2l += __shfl_down(p2l, off);
        apl += __shfl_down(apl, off);
        a2l += __shfl_down(a2l, off);
    }
    __shared__ float red[3][4];
    if ((tid & 63) == 0) {
        red[0][tid>>6] = p2l; red[1][tid>>6] = apl; red[2][tid>>6] = a2l;
    }
    __syncthreads();
    if (tid == 0) {
        const float p2 = red[0][0]+red[0][1]+red[0][2]+red[0][3];
        const float ap = red[1][0]+red[1][1]+red[1][2]+red[1][3];
        const float a2 = red[2][0]+red[2][1]+red[2][2]+red[2][3];
        const float val = a2 - 2.0f*ap + p2;
        out[OFF_LL] = sqrtf(fmaxf(val, 0.f)) / (float)kE;
        out[OFF_Z]  = 0.0f;
    }
}

// ----------------------------------------------------------------- launch
extern "C" void kernel_launch(void* const* d_in, const int* in_sizes, int n_in,
                              void* d_out, int out_size, void* d_ws, size_t ws_size,
                              hipStream_t stream)
{
    const float* x  = (const float*)d_in[0];
    const int*   ei = (const int*)d_in[1];
    const float* ew = (const float*)d_in[2];
    const float* Wm = (const float*)d_in[5];
    const float* bv = (const float*)d_in[6];
    float* out = (float*)d_out;
    char*  ws  = (char*)d_ws;
    int*   carr  = (int*)(ws + WS_C);
    float* varr  = (float*)(ws + WS_V);
    float* vs2   = (float*)(ws + WS_VS2);
    float* a2p   = (float*)(ws + WS_A2);
    int*   perm  = (int*)(ws + WS_PERM);
    int*   strt  = (int*)(ws + WS_STRT);
    unsigned short* wth = (unsigned short*)(ws + WS_WTH);
    unsigned short* wtl = (unsigned short*)(ws + WS_WTL);
    float* padj  = (float*)(ws + WS_PADJ);

    k_const    <<<2129, 256, 0, stream>>>(out, Wm, wth, wtl);
    k_logits   <<<512,  256, 0, stream>>>(x, wth, wtl, bv, carr, varr);
    k_sort     <<<64,  1024, 0, stream>>>(carr, perm, strt);
    k_pool_x   <<<512, 1024, 0, stream>>>(x, perm, strt, varr, out, vs2);
    k_adj      <<<256, 1024, 0, stream>>>(ei, ew, carr, varr, padj, a2p);
    k_adj_merge<<<1024, 256, 0, stream>>>(padj, out);
    k_final    <<<1,    256, 0, stream>>>(vs2, a2p, out);
}

// Round 15
// 75.553 us; speedup vs baseline: 2.5487x; 1.0522x over previous
//
#include <hip/hip_runtime.h>
#include <cstdint>
#include <cstddef>

typedef __attribute__((ext_vector_type(8))) short short8;
typedef __attribute__((ext_vector_type(4))) float f32x4;

#define GLOAD_LDS16(gsrc, ldst) \
    __builtin_amdgcn_global_load_lds( \
        (const __attribute__((address_space(1))) void*)(gsrc), \
        (__attribute__((address_space(3))) void*)(ldst), 16, 0, 0)

namespace {
constexpr int kN    = 65536;     // nodes
constexpr int kF    = 256;       // feats
constexpr int kC    = 64;        // pools per graph
constexpr int kNPG  = 1024;      // nodes per graph
constexpr int kB    = 64;        // graphs
constexpr int kE    = 2097152;   // edges
constexpr int kK    = kB * kC;   // 4096 global clusters

// d_out offsets (in floats)
constexpr size_t OFF_OUT  = 0;                           // [4096,256]
constexpr size_t OFF_EIDX = (size_t)kK * kF;             // 1048576  [2,262144]
constexpr size_t OFF_ADJ  = OFF_EIDX + 2ull*kB*kC*kC;    // 1572864  [262144]
constexpr size_t OFF_LL   = OFF_ADJ + (size_t)kB*kC*kC;  // 1835008
constexpr size_t OFF_Z    = OFF_LL + 1;                  // 1835009
constexpr size_t OFF_BOUT = OFF_Z + 1;                   // 1835010  [4096]
constexpr size_t OFF_BPTR = OFF_BOUT + kK;               // 1839106  [65]

// ws offsets (bytes). Overlaps stream-time-disjoint: WPH/WPL die after
// k_logits, PERM/STRT after k_pool_x; k_adj then writes PADJ (8 MB) over
// that range. vs2/a2p live below 544768 and are never overlapped.
constexpr size_t WS_C    = 0;        // int[65536]
constexpr size_t WS_V    = 262144;   // float[65536]
constexpr size_t WS_VS2  = 524288;   // float[4096]
constexpr size_t WS_A2   = 540672;   // float[512]
constexpr size_t WS_PERM = 544768;   // int[65536]
constexpr size_t WS_STRT = 806912;   // int[64*65]
constexpr size_t WS_WPH  = 1048576;  // ushort[16384] W frag-packed hi
constexpr size_t WS_WPL  = 1081344;  // ushort[16384] W frag-packed lo
constexpr size_t WS_PADJ = 544768;   // float[512*4096] = 8 MiB (k_adj onward)

__device__ __forceinline__ unsigned short bf16_rn(float f)
{
    const unsigned int b = __float_as_uint(f);
    return (unsigned short)((b + 0x7fffu + ((b >> 16) & 1u)) >> 16);
}
} // namespace

// ---------------------------------------------------------------- constants
// + packs W into MFMA B-fragment order, bf16 hi/lo:
//   wpack[((ks*4+nt)*64 + lane)*8 + j]  <-  W[(ks*32+(lane>>4)*8+j)*64
//                                             + nt*16 + (lane&15)]
// so a per-chunk fragment load is lane-contiguous 16B (fully coalesced).
__global__ __launch_bounds__(256) void k_const(float* __restrict__ out,
                                               const float* __restrict__ Wm,
                                               unsigned short* __restrict__ wph,
                                               unsigned short* __restrict__ wpl)
{
    const int i = blockIdx.x * 256 + threadIdx.x;
    constexpr int E2 = 2 * kB * kC * kC;      // 524288
    constexpr int B3 = E2 + kK + kB + 1;      // 528449
    if (i < E2) {
        const int half = i >= kB*kC*kC;
        const int idx  = half ? i - kB*kC*kC : i;
        const int bb = idx >> 12, rem = idx & 4095;
        const int val = half ? bb*kC + (rem & 63) : bb*kC + (rem >> 6);
        out[OFF_EIDX + i] = (float)val;
    } else if (i < E2 + kK) {
        const int j = i - E2;
        out[OFF_BOUT + j] = (float)(j >> 6);
    } else if (i < B3) {
        const int j = i - (E2 + kK);
        out[OFF_BPTR + j] = (float)(j * kC);
    } else if (i < B3 + 32768) {
        const int j  = (i - B3) & 16383;
        const int lo = (i - B3) >= 16384;
        const int jj = j & 7, lane = (j >> 3) & 63;
        const int nt = (j >> 9) & 3, ks = j >> 11;
        const float wv = Wm[(size_t)(ks*32 + (lane>>4)*8 + jj)*kC
                            + nt*16 + (lane & 15)];
        const unsigned short h = bf16_rn(wv);
        if (!lo) {
            wph[j] = h;
        } else {
            const float hf = __uint_as_float((unsigned int)h << 16);
            wpl[j] = bf16_rn(wv - hf);
        }
    }
}

// ------------------------------------------------- K1: logits -> c, v
// m97-style staged MFMA, round-14 structure with two fixes:
//  (1) W fragments load COALESCED from the frag-packed wph/wpl (16B
//      lane-contiguous -> 1 L1 line-burst vs 64 scattered lines/instr).
//  (2) x LDS T2-swizzled: stage source pre-swizzled per-lane (slot
//      sigma=(l&7)^(l>>3)), LDS dest linear (global_load_lds rule #21);
//      reader XORs slot with row&7 -> 16-way bank conflict becomes 2-way.
// Numerics identical to rounds 13/14 (same values, same MFMA order).
__global__ __launch_bounds__(256) void k_logits(
    const float* __restrict__ x, const unsigned short* __restrict__ wph,
    const unsigned short* __restrict__ wpl, const float* __restrict__ bv,
    int* __restrict__ carr, float* __restrict__ varr)
{
    __shared__ float xs[2][128 * 32];   // 2 x 16 KB, [node][8 slots x 4f]
    const int tid  = threadIdx.x;
    const int lane = tid & 63;
    const int w    = tid >> 6;          // wave 0..3
    const int nbase = blockIdx.x * 128;
    const int l15  = lane & 15;
    const int kgrp = lane >> 4;         // 0..3

    // staging: wave w stages groups g=w*4+i (8 nodes x 128B); lane l ->
    // node g*8+(l>>3), physical slot l&7 holds k-slot (l&7)^(l>>3).
    const int snode = lane >> 3;                         // 0..7 = node&7
    const int sfo   = (((lane & 7) ^ snode)) * 4;        // src float offset

    f32x4 acc[2][4];
#pragma unroll
    for (int mt = 0; mt < 2; ++mt)
#pragma unroll
        for (int nt = 0; nt < 4; ++nt)
            acc[mt][nt] = f32x4{0.f, 0.f, 0.f, 0.f};

    // prologue: stage chunk 0 into buffer 0
#pragma unroll
    for (int i = 0; i < 4; ++i) {
        const int g = w*4 + i;
        const float* src = x + (size_t)(nbase + g*8 + snode)*kF + sfo;
        GLOAD_LDS16(src, &xs[0][g*256]);
    }

#pragma unroll 1
    for (int c = 0; c < 8; ++c) {
        if (c < 7) {
#pragma unroll
            for (int i = 0; i < 4; ++i) {
                const int g = w*4 + i;
                const float* src = x + (size_t)(nbase + g*8 + snode)*kF
                                     + (c+1)*32 + sfo;
                GLOAD_LDS16(src, &xs[(c+1) & 1][g*256]);
            }
            asm volatile("s_waitcnt vmcnt(4)" ::: "memory");
        } else {
            asm volatile("s_waitcnt vmcnt(0)" ::: "memory");
        }
        __syncthreads();   // chunk c landed for all waves; old buf free

        const float* __restrict__ xb = &xs[c & 1][0];
        // W fragments: coalesced 16B/lane from frag-packed arrays
        short8 bh[4], bl[4];
#pragma unroll
        for (int nt = 0; nt < 4; ++nt) {
            const size_t wo = ((size_t)(c*4 + nt)*64 + lane) * 8;
            bh[nt] = *reinterpret_cast<const short8*>(wph + wo);
            bl[nt] = *reinterpret_cast<const short8*>(wpl + wo);
        }
#pragma unroll
        for (int mt = 0; mt < 2; ++mt) {
            const int row = w*32 + mt*16 + l15;
            const int sA  = ((kgrp*2)     ^ (row & 7)) * 4;
            const int sC  = ((kgrp*2 + 1) ^ (row & 7)) * 4;
            const float4 xa = *reinterpret_cast<const float4*>(
                &xb[row*32 + sA]);
            const float4 xc = *reinterpret_cast<const float4*>(
                &xb[row*32 + sC]);
            const float xv[8] = {xa.x, xa.y, xa.z, xa.w,
                                 xc.x, xc.y, xc.z, xc.w};
            short8 ah, al;
#pragma unroll
            for (int j = 0; j < 8; ++j) {
                const unsigned short h = bf16_rn(xv[j]);
                const float hf = __uint_as_float((unsigned int)h << 16);
                ah[j] = (short)h;
                al[j] = (short)bf16_rn(xv[j] - hf);
            }
#pragma unroll
            for (int nt = 0; nt < 4; ++nt) {
                acc[mt][nt] = __builtin_amdgcn_mfma_f32_16x16x32_bf16(
                    ah, bh[nt], acc[mt][nt], 0, 0, 0);
                acc[mt][nt] = __builtin_amdgcn_mfma_f32_16x16x32_bf16(
                    al, bh[nt], acc[mt][nt], 0, 0, 0);
                acc[mt][nt] = __builtin_amdgcn_mfma_f32_16x16x32_bf16(
                    ah, bl[nt], acc[mt][nt], 0, 0, 0);
                acc[mt][nt] = __builtin_amdgcn_mfma_f32_16x16x32_bf16(
                    al, bl[nt], acc[mt][nt], 0, 0, 0);
            }
        }
        __syncthreads();   // all waves done reading buf[c&1]
    }

    // bias + per-node softmax-argmax (D: col=nt*16+l15, row=kgrp*4+r)
#pragma unroll
    for (int mt = 0; mt < 2; ++mt) {
#pragma unroll
        for (int nt = 0; nt < 4; ++nt) {
            const float b = bv[nt*16 + l15];
#pragma unroll
            for (int r = 0; r < 4; ++r) acc[mt][nt][r] += b;
        }
#pragma unroll
        for (int r = 0; r < 4; ++r) {
            float m = acc[mt][0][r]; int ci = l15;
#pragma unroll
            for (int nt = 1; nt < 4; ++nt) {
                if (acc[mt][nt][r] > m) { m = acc[mt][nt][r]; ci = nt*16 + l15; }
            }
#pragma unroll
            for (int off = 1; off < 16; off <<= 1) {
                const float om = __shfl_xor(m, off);
                const int   oc = __shfl_xor(ci, off);
                if (om > m || (om == m && oc < ci)) { m = om; ci = oc; }
            }
            float s = 0.f;
#pragma unroll
            for (int nt = 0; nt < 4; ++nt) s += expf(acc[mt][nt][r] - m);
#pragma unroll
            for (int off = 1; off < 16; off <<= 1) s += __shfl_xor(s, off);
            if (l15 == r) {
                const float p = 1.0f / s;
                const int n = nbase + w*32 + mt*16 + kgrp*4 + r;
                carr[n] = ci;
                varr[n] = (1.0f - p) + p;   // straight-through forward
            }
        }
    }
}

// ------------------------------------- K1b: deterministic stable counting sort
__global__ __launch_bounds__(1024) void k_sort(
    const int* __restrict__ carr, int* __restrict__ perm,
    int* __restrict__ startc)
{
    __shared__ int hist[16][64];
    __shared__ int startS[65];
    const int g = blockIdx.x;
    const int tid = threadIdx.x;
    const int w = tid >> 6, lane = tid & 63;
    const int c = carr[g*kNPG + tid];
    hist[tid >> 6][tid & 63] = 0;
    __syncthreads();
    unsigned long long mm = ~0ull;
#pragma unroll
    for (int b = 0; b < 6; ++b) {
        const unsigned long long bal = __ballot((c >> b) & 1);
        mm &= ((c >> b) & 1) ? bal : ~bal;
    }
    const unsigned long long ltmask =
        (lane == 0) ? 0ull : (~0ull >> (64 - lane));
    const int rank_in_wave = __popcll(mm & ltmask);
    const int leader = __ffsll((unsigned long long)mm) - 1;
    if (lane == leader) hist[w][c] = __popcll(mm);
    __syncthreads();
    if (w == 0) {
        int tot = 0;
#pragma unroll
        for (int i = 0; i < 16; ++i) tot += hist[i][lane];
        int pre = tot;
#pragma unroll
        for (int off = 1; off < 64; off <<= 1) {
            const int t = __shfl_up(pre, off);
            if (lane >= off) pre += t;
        }
        startS[lane + 1] = pre;
        if (lane == 0) startS[0] = 0;
    }
    __syncthreads();
    int before = startS[c];
    for (int i = 0; i < w; ++i) before += hist[i][c];
    perm[g*kNPG + before + rank_in_wave] = g*kNPG + tid;
    if (tid < 65) startc[g*65 + tid] = startS[tid];
}

// ------------------------------------- K2: out = S^T x (+ vs2) — atomic-FREE
__global__ __launch_bounds__(1024) void k_pool_x(
    const float* __restrict__ x, const int* __restrict__ perm,
    const int* __restrict__ startc, const float* __restrict__ varr,
    float* __restrict__ out, float* __restrict__ vs2)
{
    const int tid  = threadIdx.x;
    const int g    = blockIdx.x >> 3;
    const int fh   = blockIdx.x & 7;
    const int w    = tid >> 6;
    const int lane = tid & 63;
    const int q    = lane & 7;      // feat quad (float4)
    const int sub  = lane >> 3;     // node slot 0..7
    const int fbase = fh*32 + q*4;
#pragma unroll
    for (int cc = 0; cc < 4; ++cc) {
        const int c = w*4 + cc;
        const int s = startc[g*65 + c];
        const int e = startc[g*65 + c + 1];
        float ax = 0.f, ay = 0.f, az = 0.f, aw = 0.f, v2 = 0.f;
        for (int base = s + sub; base < e; base += 8) {
            const int n = perm[(size_t)g*kNPG + base];
            const float v = varr[n];
            const float4 xv = *reinterpret_cast<const float4*>(
                x + (size_t)n*kF + fbase);
            ax = fmaf(v, xv.x, ax); ay = fmaf(v, xv.y, ay);
            az = fmaf(v, xv.z, az); aw = fmaf(v, xv.w, aw);
            v2 = fmaf(v, v, v2);
        }
#pragma unroll
        for (int off = 8; off < 64; off <<= 1) {
            ax += __shfl_xor(ax, off); ay += __shfl_xor(ay, off);
            az += __shfl_xor(az, off); aw += __shfl_xor(aw, off);
            v2 += __shfl_xor(v2, off);
        }
        if (sub == 0) {
            const float4 o = {ax, ay, az, aw};
            *reinterpret_cast<float4*>(
                out + OFF_OUT + (size_t)(g*kC + c)*kF + fbase) = o;
        }
        if (fh == 0 && lane == 0) vs2[g*kC + c] = v2;
    }
}

// ------------------------------------- K4: adjacency partials (+ a2 partial)
// 512 blocks (4096 edges each): halves per-block LDS-atomic serialization.
__global__ __launch_bounds__(1024) void k_adj(
    const int* __restrict__ ei, const float* __restrict__ ew,
    const int* __restrict__ carr, const float* __restrict__ varr,
    float* __restrict__ padj, float* __restrict__ a2p)
{
    __shared__ float adj[kC*kC];   // 16 KB
    __shared__ float vls[kNPG];    // 4 KB
    __shared__ int   cls[kNPG];    // 4 KB
    __shared__ float wred[16];
    const int tid = threadIdx.x;
    const int bid = blockIdx.x;             // 512 blocks = 64 graphs x 8
    const int g   = bid >> 3;
    for (int i = tid; i < kC*kC; i += 1024) adj[i] = 0.f;
    vls[tid] = varr[g*kNPG + tid];
    cls[tid] = carr[g*kNPG + tid];
    __syncthreads();
    const int e0 = bid * 4096;
    float a2l = 0.f;
#pragma unroll
    for (int it = 0; it < 4; ++it) {
        const int e  = e0 + it*1024 + tid;
        const int sn = ei[e]      & (kNPG - 1);
        const int dn = ei[kE + e] & (kNPG - 1);
        const float wv = ew[e];
        a2l += wv * wv;
        atomicAdd(&adj[cls[sn]*kC + cls[dn]], wv * vls[sn] * vls[dn]);
    }
    __syncthreads();
#pragma unroll
    for (int r = 0; r < 4; ++r) {
        const int lin = r*1024 + tid;
        padj[(size_t)bid*4096 + lin] = adj[lin];
    }
#pragma unroll
    for (int off = 32; off > 0; off >>= 1) a2l += __shfl_down(a2l, off);
    if ((tid & 63) == 0) wred[tid >> 6] = a2l;
    __syncthreads();
    if (tid == 0) {
        float s = 0.f;
#pragma unroll
        for (int wv = 0; wv < 16; ++wv) s += wred[wv];
        a2p[bid] = s;
    }
}

// ------------------------------------- K5: merge adjacency partials (x8)
__global__ __launch_bounds__(256) void k_adj_merge(
    const float* __restrict__ padj, float* __restrict__ out)
{
    const int id = blockIdx.x*256 + threadIdx.x;   // < 262144
    const int g = id >> 12, idx = id & 4095;
    float s = 0.f;
#pragma unroll
    for (int sp = 0; sp < 8; ++sp) s += padj[(size_t)(g*8 + sp)*4096 + idx];
    out[OFF_ADJ + id] = s;
}

// ------------------------------------- K6: link_loss scalar
__global__ __launch_bounds__(256) void k_final(
    const float* __restrict__ vs2, const float* __restrict__ a2p,
    float* __restrict__ out)
{
    const int tid = threadIdx.x;
    float p2l = 0.f, apl = 0.f;
#pragma unroll
    for (int r = 0; r < 16; ++r) {
        const int k = r*256 + tid;
        const float t = vs2[k];
        p2l += t*t;
        const int g = k >> 6, cc = k & 63;
        apl += out[OFF_ADJ + (size_t)g*4096 + cc*65];   // diagonal entries
    }
    float a2l = a2p[tid] + a2p[tid + 256];
#pragma unroll
    for (int off = 32; off > 0; off >>= 1) {
        p2l += __shfl_down(p2l, off);
        apl += __shfl_down(apl, off);
        a2l += __shfl_down(a2l, off);
    }
    __shared__ float red[3][4];
    if ((tid & 63) == 0) {
        red[0][tid>>6] = p2l; red[1][tid>>6] = apl; red[2][tid>>6] = a2l;
    }
    __syncthreads();
    if (tid == 0) {
        const float p2 = red[0][0]+red[0][1]+red[0][2]+red[0][3];
        const float ap = red[1][0]+red[1][1]+red[1][2]+red[1][3];
        const float a2 = red[2][0]+red[2][1]+red[2][2]+red[2][3];
        const float val = a2 - 2.0f*ap + p2;
        out[OFF_LL] = sqrtf(fmaxf(val, 0.f)) / (float)kE;
        out[OFF_Z]  = 0.0f;
    }
}

// ----------------------------------------------------------------- launch
extern "C" void kernel_launch(void* const* d_in, const int* in_sizes, int n_in,
                              void* d_out, int out_size, void* d_ws, size_t ws_size,
                              hipStream_t stream)
{
    const float* x  = (const float*)d_in[0];
    const int*   ei = (const int*)d_in[1];
    const float* ew = (const float*)d_in[2];
    const float* Wm = (const float*)d_in[5];
    const float* bv = (const float*)d_in[6];
    float* out = (float*)d_out;
    char*  ws  = (char*)d_ws;
    int*   carr  = (int*)(ws + WS_C);
    float* varr  = (float*)(ws + WS_V);
    float* vs2   = (float*)(ws + WS_VS2);
    float* a2p   = (float*)(ws + WS_A2);
    int*   perm  = (int*)(ws + WS_PERM);
    int*   strt  = (int*)(ws + WS_STRT);
    unsigned short* wph = (unsigned short*)(ws + WS_WPH);
    unsigned short* wpl = (unsigned short*)(ws + WS_WPL);
    float* padj  = (float*)(ws + WS_PADJ);

    k_const    <<<2193, 256, 0, stream>>>(out, Wm, wph, wpl);
    k_logits   <<<512,  256, 0, stream>>>(x, wph, wpl, bv, carr, varr);
    k_sort     <<<64,  1024, 0, stream>>>(carr, perm, strt);
    k_pool_x   <<<512, 1024, 0, stream>>>(x, perm, strt, varr, out, vs2);
    k_adj      <<<512, 1024, 0, stream>>>(ei, ew, carr, varr, padj, a2p);
    k_adj_merge<<<1024, 256, 0, stream>>>(padj, out);
    k_final    <<<1,    256, 0, stream>>>(vs2, a2p, out);
}